// Round 1
// baseline (438.711 us; speedup 1.0000x reference)
//
#include <hip/hip_runtime.h>

typedef unsigned short u16;
typedef unsigned int   u32;
typedef unsigned long long u64;
typedef __bf16 bf16x8 __attribute__((ext_vector_type(8)));
typedef float  f32x4  __attribute__((ext_vector_type(4)));

#define AS1 __attribute__((address_space(1)))
#define AS3 __attribute__((address_space(3)))

#define M_TOK   8192
#define K_DIM   4096
#define N_DIM   4096

static __device__ __forceinline__ u16 f2bf(float f) {
  u32 u = __builtin_bit_cast(u32, f);
  return (u16)((u + (0x7FFFu + ((u >> 16) & 1u))) >> 16);
}

// global -> LDS direct copy, 16B per lane. LDS dest must be wave-uniform;
// HW stores lane l at dest + l*16 (linear, no swizzle - rule #21).
static __device__ __forceinline__ void gld_lds16(const void* g, void* l) {
  __builtin_amdgcn_global_load_lds((AS1 u32*)(u64)g, (AS3 u32*)(u32)(u64)l, 16, 0, 0);
}

// ---- W_main f32 -> bf16 ----
__global__ __launch_bounds__(256) void k_conv_w(const float* __restrict__ W,
                                                u16* __restrict__ Wb, int n4) {
  const float4* W4 = (const float4*)W;
  ushort4* Wb4 = (ushort4*)Wb;
  int i = blockIdx.x * 256 + threadIdx.x;
  const int stride = gridDim.x * 256;
  for (; i < n4; i += stride) {
    float4 v = W4[i];
    ushort4 o;
    o.x = f2bf(v.x); o.y = f2bf(v.y); o.z = f2bf(v.z); o.w = f2bf(v.w);
    Wb4[i] = o;
  }
}

// ---- per token row: x f32 -> bf16, and mid[m][r] = 2 * dot(x[m], W_A[r]) ----
__global__ __launch_bounds__(256) void k_prep_x(const float* __restrict__ x,
                                                const float* __restrict__ WA,
                                                u16* __restrict__ xb,
                                                float* __restrict__ mid) {
  const int m = blockIdx.x;
  const int t = threadIdx.x;
  const float4* xr = (const float4*)(x + (size_t)m * K_DIM);
  ushort4* xbr = (ushort4*)(xb + (size_t)m * K_DIM);
  float a[8] = {0.f,0.f,0.f,0.f,0.f,0.f,0.f,0.f};
  #pragma unroll
  for (int i = 0; i < 4; ++i) {
    const int k4 = t + i * 256;
    float4 v = xr[k4];
    ushort4 o;
    o.x = f2bf(v.x); o.y = f2bf(v.y); o.z = f2bf(v.z); o.w = f2bf(v.w);
    xbr[k4] = o;
    #pragma unroll
    for (int r = 0; r < 8; ++r) {
      float4 wv = ((const float4*)(WA + (size_t)r * K_DIM))[k4];
      a[r] += v.x * wv.x + v.y * wv.y + v.z * wv.z + v.w * wv.w;
    }
  }
  #pragma unroll
  for (int r = 0; r < 8; ++r) {
    #pragma unroll
    for (int off = 32; off > 0; off >>= 1)
      a[r] += __shfl_down(a[r], off);
  }
  __shared__ float red[4][8];
  const int w = t >> 6, l = t & 63;
  if (l == 0) {
    #pragma unroll
    for (int r = 0; r < 8; ++r) red[w][r] = a[r];
  }
  __syncthreads();
  if (t < 8)
    mid[(size_t)m * 8 + t] = 2.0f * (red[0][t] + red[1][t] + red[2][t] + red[3][t]);
}

// ---- main GEMM: out = A(bf16) * B(bf16)^T + bias + mask * (mid . W_B) ----
// A = xb [8192][4096], B = wb [4096][4096], both row-major, K contiguous.
// 128x128 tile, BK=32, 4 waves (2x2), 4x4 16x16x32 fragments per wave.
__global__ __launch_bounds__(256) void k_gemm(
    const u16* __restrict__ A, const u16* __restrict__ B,
    const float* __restrict__ bias, const int* __restrict__ mask,
    const float* __restrict__ mid, const float* __restrict__ WBw,
    float* __restrict__ out) {
  __shared__ u16 As[128][32];
  __shared__ u16 Bs[128][32];

  const int t = threadIdx.x;
  const int w = t >> 6, l = t & 63;
  const int wr = w >> 1, wc = w & 1;       // wave -> 64x64 quadrant
  const int fr = l & 15, fq = l >> 4;      // fragment row / k-group
  const int bm = blockIdx.y, bn = blockIdx.x;

  const char* Ag = (const char*)(A + (size_t)bm * 128 * K_DIM);
  const char* Bg = (const char*)(B + (size_t)bn * 128 * K_DIM);
  const size_t rowb = (size_t)K_DIM * 2;   // 8192 B per row
  const int srow = w * 32 + (l >> 2);      // staging row within tile
  const int scol = (l & 3) * 16;           // byte offset within 64B k-chunk

  void* AsD0 = (void*)&As[w * 32][0];
  void* AsD1 = (void*)&As[w * 32 + 16][0];
  void* BsD0 = (void*)&Bs[w * 32][0];
  void* BsD1 = (void*)&Bs[w * 32 + 16][0];

  f32x4 acc[4][4];
  #pragma unroll
  for (int m = 0; m < 4; ++m)
    #pragma unroll
    for (int n = 0; n < 4; ++n)
      acc[m][n] = (f32x4){0.f, 0.f, 0.f, 0.f};

  for (int kt = 0; kt < K_DIM / 32; ++kt) {
    const char* a0 = Ag + (size_t)srow * rowb + (size_t)kt * 64 + scol;
    const char* b0 = Bg + (size_t)srow * rowb + (size_t)kt * 64 + scol;
    gld_lds16(a0, AsD0);
    gld_lds16(a0 + 16 * rowb, AsD1);
    gld_lds16(b0, BsD0);
    gld_lds16(b0 + 16 * rowb, BsD1);
    __syncthreads();   // compiler drains vmcnt before s_barrier -> LDS valid
    bf16x8 af[4], bfv[4];
    #pragma unroll
    for (int m = 0; m < 4; ++m)
      af[m] = *(const bf16x8*)&As[wr * 64 + m * 16 + fr][fq * 8];
    #pragma unroll
    for (int n = 0; n < 4; ++n)
      bfv[n] = *(const bf16x8*)&Bs[wc * 64 + n * 16 + fr][fq * 8];
    #pragma unroll
    for (int m = 0; m < 4; ++m)
      #pragma unroll
      for (int n = 0; n < 4; ++n)
        acc[m][n] = __builtin_amdgcn_mfma_f32_16x16x32_bf16(af[m], bfv[n], acc[m][n], 0, 0, 0);
    __syncthreads();   // all waves done reading before next stage overwrites
  }

  // ---- epilogue: bias + masked rank-8 LoRA, fp32 out ----
  const int gn0 = bn * 128 + wc * 64;
  const size_t gm0 = (size_t)bm * 128 + wr * 64;
  float wbv[4][8]; float bv[4];
  #pragma unroll
  for (int n = 0; n < 4; ++n) {
    const int gn = gn0 + n * 16 + fr;
    bv[n] = bias[gn];
    const float4 w0 = ((const float4*)(WBw + (size_t)gn * 8))[0];
    const float4 w1 = ((const float4*)(WBw + (size_t)gn * 8))[1];
    wbv[n][0] = w0.x; wbv[n][1] = w0.y; wbv[n][2] = w0.z; wbv[n][3] = w0.w;
    wbv[n][4] = w1.x; wbv[n][5] = w1.y; wbv[n][6] = w1.z; wbv[n][7] = w1.w;
  }
  #pragma unroll
  for (int m = 0; m < 4; ++m) {
    #pragma unroll
    for (int j = 0; j < 4; ++j) {
      const size_t gm = gm0 + m * 16 + fq * 4 + j;   // C/D row = (l>>4)*4 + reg
      const int msk = mask[gm];
      const float4 m0 = ((const float4*)(mid + gm * 8))[0];
      const float4 m1 = ((const float4*)(mid + gm * 8))[1];
      float* orow = out + gm * (size_t)N_DIM;
      #pragma unroll
      for (int n = 0; n < 4; ++n) {
        const float lora =
            m0.x * wbv[n][0] + m0.y * wbv[n][1] + m0.z * wbv[n][2] + m0.w * wbv[n][3] +
            m1.x * wbv[n][4] + m1.y * wbv[n][5] + m1.z * wbv[n][6] + m1.w * wbv[n][7];
        const float v = acc[m][n][j] + bv[n] + (msk ? lora : 0.0f);
        orow[gn0 + n * 16 + fr] = v;                 // C/D col = l&15
      }
    }
  }
}

extern "C" void kernel_launch(void* const* d_in, const int* in_sizes, int n_in,
                              void* d_out, int out_size, void* d_ws, size_t ws_size,
                              hipStream_t stream) {
  (void)in_sizes; (void)n_in; (void)out_size; (void)ws_size;
  const float* x     = (const float*)d_in[0];
  const int*   mask  = (const int*)d_in[1];
  const float* Wm    = (const float*)d_in[2];
  const float* bmain = (const float*)d_in[3];
  const float* WA    = (const float*)d_in[4];
  const float* WB    = (const float*)d_in[5];
  float* out = (float*)d_out;

  u16* xb  = (u16*)d_ws;                                // 64 MiB
  u16* wb  = xb + (size_t)M_TOK * K_DIM;                // 32 MiB
  float* mid = (float*)(wb + (size_t)N_DIM * K_DIM);    // 256 KiB

  k_conv_w<<<2048, 256, 0, stream>>>(Wm, wb, (N_DIM * K_DIM) / 4);
  k_prep_x<<<M_TOK, 256, 0, stream>>>(x, WA, xb, mid);
  dim3 grid(N_DIM / 128, M_TOK / 128);
  k_gemm<<<grid, 256, 0, stream>>>(xb, wb, bmain, mask, mid, WB, out);
}

// Round 2
// 362.064 us; speedup vs baseline: 1.2117x; 1.2117x over previous
//
#include <hip/hip_runtime.h>

typedef unsigned short u16;
typedef unsigned int   u32;
typedef unsigned long long u64;
typedef __bf16 bf16x8 __attribute__((ext_vector_type(8)));
typedef float  f32x4  __attribute__((ext_vector_type(4)));

#define AS1 __attribute__((address_space(1)))
#define AS3 __attribute__((address_space(3)))

#define M_TOK 8192
#define K_DIM 4096
#define N_DIM 4096
#define BK    32
#define NKT   (K_DIM / BK)   // 128

static __device__ __forceinline__ u16 f2bf(float f) {
  u32 u = __builtin_bit_cast(u32, f);
  return (u16)((u + (0x7FFFu + ((u >> 16) & 1u))) >> 16);
}

// global -> LDS direct copy, 16B per lane. LDS dest is wave-uniform base;
// HW stores lane l at dest + l*16 (linear, rule #21).
static __device__ __forceinline__ void gld_lds16(const void* g, void* l) {
  __builtin_amdgcn_global_load_lds((AS1 u32*)(u64)g, (AS3 u32*)(u32)(u64)l, 16, 0, 0);
}

// ---- W_main f32 -> bf16 ----
__global__ __launch_bounds__(256) void k_conv_w(const float* __restrict__ W,
                                                u16* __restrict__ Wb, int n4) {
  const float4* W4 = (const float4*)W;
  ushort4* Wb4 = (ushort4*)Wb;
  int i = blockIdx.x * 256 + threadIdx.x;
  const int stride = gridDim.x * 256;
  for (; i < n4; i += stride) {
    float4 v = W4[i];
    ushort4 o;
    o.x = f2bf(v.x); o.y = f2bf(v.y); o.z = f2bf(v.z); o.w = f2bf(v.w);
    Wb4[i] = o;
  }
}

// ---- per token row: x f32 -> bf16, and mid[m][r] = 2 * dot(x[m], W_A[r]) ----
__global__ __launch_bounds__(256) void k_prep_x(const float* __restrict__ x,
                                                const float* __restrict__ WA,
                                                u16* __restrict__ xb,
                                                float* __restrict__ mid) {
  const int m = blockIdx.x;
  const int t = threadIdx.x;
  const float4* xr = (const float4*)(x + (size_t)m * K_DIM);
  ushort4* xbr = (ushort4*)(xb + (size_t)m * K_DIM);
  float a[8] = {0.f,0.f,0.f,0.f,0.f,0.f,0.f,0.f};
  #pragma unroll
  for (int i = 0; i < 4; ++i) {
    const int k4 = t + i * 256;
    float4 v = xr[k4];
    ushort4 o;
    o.x = f2bf(v.x); o.y = f2bf(v.y); o.z = f2bf(v.z); o.w = f2bf(v.w);
    xbr[k4] = o;
    #pragma unroll
    for (int r = 0; r < 8; ++r) {
      float4 wv = ((const float4*)(WA + (size_t)r * K_DIM))[k4];
      a[r] += v.x * wv.x + v.y * wv.y + v.z * wv.z + v.w * wv.w;
    }
  }
  #pragma unroll
  for (int r = 0; r < 8; ++r) {
    #pragma unroll
    for (int off = 32; off > 0; off >>= 1)
      a[r] += __shfl_down(a[r], off);
  }
  __shared__ float red[4][8];
  const int w = t >> 6, l = t & 63;
  if (l == 0) {
    #pragma unroll
    for (int r = 0; r < 8; ++r) red[w][r] = a[r];
  }
  __syncthreads();
  if (t < 8)
    mid[(size_t)m * 8 + t] = 2.0f * (red[0][t] + red[1][t] + red[2][t] + red[3][t]);
}

// ---- main GEMM: 256x256 tile, BK=32, 8 waves (2Mx4N), 4-deep LDS ring,
// counted-vmcnt pipeline (T3+T4) + setprio (T5) + XCD swizzle (T1). ----
// Wait ledger (per wave, 4 gld_lds per tile, FIFO vmcnt retire):
//   prologue: issue tiles 0,1,2 (12 loads); vmcnt(8) -> tile0 resident.
//   during tile kt: issue tile kt+3 into buf (kt+3)&3 (= buf of kt-1,
//     whose reads finished before kt began -> no read/write race).
//   end of kt: need tile kt+1 (issued during kt-2) resident. Loads younger
//     than it: tiles kt+2,kt+3 = 8 -> vmcnt(8). Tail: 8 -> 4 -> 0.
__global__ __launch_bounds__(512, 2) void k_gemm(
    const u16* __restrict__ A, const u16* __restrict__ B,
    const float* __restrict__ bias, const int* __restrict__ mask,
    const float* __restrict__ mid, const float* __restrict__ WBw,
    float* __restrict__ out) {
  __shared__ u16 smem[4][2][256][BK];   // [buf][A=0/B=1][row][k] = 128 KiB

  const int t = threadIdx.x;
  const int wid = t >> 6, l = t & 63;
  const int wr = wid >> 2, wc = wid & 3;   // 2x4 wave grid -> 128x64 out/wave
  const int fr = l & 15, fq = l >> 4;

  // T1: XCD-aware swizzle (512 blocks, 512%8==0 -> simple bijective form)
  const int bid = blockIdx.x;
  const int swz = (bid & 7) * 64 + (bid >> 3);
  const int bm = swz >> 4, bn = swz & 15;

  const char* Ag = (const char*)(A + (size_t)bm * 256 * K_DIM);
  const char* Bg = (const char*)(B + (size_t)bn * 256 * K_DIM);
  const size_t rowb = (size_t)K_DIM * 2;

  // staging: round q in {0:A-lo,1:A-hi,2:B-lo,3:B-hi}; 512 thr x 16B = 8KB
  // = one 128-row x 64B half. thread t covers row t>>2, 16B-chunk t&3.
  const int srow = t >> 2;
  const int schk = (t & 3) * 16;
  const char* gsrc[4] = {
    Ag + (size_t)srow * rowb + schk,
    Ag + (size_t)(128 + srow) * rowb + schk,
    Bg + (size_t)srow * rowb + schk,
    Bg + (size_t)(128 + srow) * rowb + schk };
  char* lbase = (char*)&smem[0][0][0][0] + wid * 1024;

  #define STAGE(bufv, nktv, q) \
    gld_lds16(gsrc[q] + (size_t)(nktv) * (BK * 2), \
              lbase + (bufv) * 32768 + (q) * 8192)

  f32x4 acc[8][4];
  #pragma unroll
  for (int m = 0; m < 8; ++m)
    #pragma unroll
    for (int n = 0; n < 4; ++n)
      acc[m][n] = (f32x4){0.f, 0.f, 0.f, 0.f};

  // prologue: tiles 0..2
  #pragma unroll
  for (int pk = 0; pk < 3; ++pk) {
    STAGE(pk, pk, 0); STAGE(pk, pk, 1); STAGE(pk, pk, 2); STAGE(pk, pk, 3);
  }
  asm volatile("s_waitcnt vmcnt(8)");
  __builtin_amdgcn_s_barrier();

  bf16x8 bfv[4];
  for (int kt = 0; kt < NKT; ++kt) {
    const int buf = kt & 3;
    const int nkt = kt + 3;
    const int nbuf = nkt & 3;
    const bool st = nkt < NKT;
    const u16* Ab = &smem[buf][0][wr * 128 + fr][fq * 8];
    const u16* Bb = &smem[buf][1][wc * 64 + fr][fq * 8];
    bf16x8 af[4];

    // ---- phase 0: frags m0..3 + all b; stage A halves of kt+3 ----
    #pragma unroll
    for (int m = 0; m < 4; ++m) af[m] = *(const bf16x8*)(Ab + m * 16 * BK);
    #pragma unroll
    for (int n = 0; n < 4; ++n) bfv[n] = *(const bf16x8*)(Bb + n * 16 * BK);
    if (st) { STAGE(nbuf, nkt, 0); STAGE(nbuf, nkt, 1); }
    __builtin_amdgcn_s_barrier();
    asm volatile("s_waitcnt lgkmcnt(0)");
    __builtin_amdgcn_s_setprio(1);
    #pragma unroll
    for (int m = 0; m < 4; ++m)
      #pragma unroll
      for (int n = 0; n < 4; ++n)
        acc[m][n] = __builtin_amdgcn_mfma_f32_16x16x32_bf16(af[m], bfv[n], acc[m][n], 0, 0, 0);
    __builtin_amdgcn_s_setprio(0);
    __builtin_amdgcn_s_barrier();

    // ---- phase 1: frags m4..7; stage B halves of kt+3; tile-end vmcnt ----
    #pragma unroll
    for (int m = 0; m < 4; ++m) af[m] = *(const bf16x8*)(Ab + (4 + m) * 16 * BK);
    if (st) { STAGE(nbuf, nkt, 2); STAGE(nbuf, nkt, 3); }
    if (kt <= NKT - 4)      asm volatile("s_waitcnt vmcnt(8)");
    else if (kt == NKT - 3) asm volatile("s_waitcnt vmcnt(4)");
    else if (kt == NKT - 2) asm volatile("s_waitcnt vmcnt(0)");
    __builtin_amdgcn_s_barrier();
    asm volatile("s_waitcnt lgkmcnt(0)");
    __builtin_amdgcn_s_setprio(1);
    #pragma unroll
    for (int m = 0; m < 4; ++m)
      #pragma unroll
      for (int n = 0; n < 4; ++n)
        acc[4 + m][n] = __builtin_amdgcn_mfma_f32_16x16x32_bf16(af[m], bfv[n], acc[4 + m][n], 0, 0, 0);
    __builtin_amdgcn_s_setprio(0);
    __builtin_amdgcn_s_barrier();
  }
  #undef STAGE

  // ---- epilogue: bias + masked rank-8 LoRA, fp32 out ----
  const int gn0 = bn * 256 + wc * 64;
  const size_t gm0 = (size_t)bm * 256 + wr * 128;
  float wbv[4][8]; float bv[4];
  #pragma unroll
  for (int n = 0; n < 4; ++n) {
    const int gn = gn0 + n * 16 + fr;
    bv[n] = bias[gn];
    const float4 w0 = ((const float4*)(WBw + (size_t)gn * 8))[0];
    const float4 w1 = ((const float4*)(WBw + (size_t)gn * 8))[1];
    wbv[n][0] = w0.x; wbv[n][1] = w0.y; wbv[n][2] = w0.z; wbv[n][3] = w0.w;
    wbv[n][4] = w1.x; wbv[n][5] = w1.y; wbv[n][6] = w1.z; wbv[n][7] = w1.w;
  }
  #pragma unroll
  for (int m = 0; m < 8; ++m) {
    #pragma unroll
    for (int j = 0; j < 4; ++j) {
      const size_t gm = gm0 + m * 16 + fq * 4 + j;   // C/D row = (l>>4)*4+reg
      const int msk = mask[gm];
      const float4 m0 = ((const float4*)(mid + gm * 8))[0];
      const float4 m1 = ((const float4*)(mid + gm * 8))[1];
      float* orow = out + gm * (size_t)N_DIM;
      #pragma unroll
      for (int n = 0; n < 4; ++n) {
        const float lora =
            m0.x * wbv[n][0] + m0.y * wbv[n][1] + m0.z * wbv[n][2] + m0.w * wbv[n][3] +
            m1.x * wbv[n][4] + m1.y * wbv[n][5] + m1.z * wbv[n][6] + m1.w * wbv[n][7];
        orow[gn0 + n * 16 + fr] = acc[m][n][j] + bv[n] + (msk ? lora : 0.0f);
      }
    }
  }
}

extern "C" void kernel_launch(void* const* d_in, const int* in_sizes, int n_in,
                              void* d_out, int out_size, void* d_ws, size_t ws_size,
                              hipStream_t stream) {
  (void)in_sizes; (void)n_in; (void)out_size; (void)ws_size;
  const float* x     = (const float*)d_in[0];
  const int*   mask  = (const int*)d_in[1];
  const float* Wm    = (const float*)d_in[2];
  const float* bmain = (const float*)d_in[3];
  const float* WA    = (const float*)d_in[4];
  const float* WB    = (const float*)d_in[5];
  float* out = (float*)d_out;

  u16* xb  = (u16*)d_ws;                                // 64 MiB
  u16* wb  = xb + (size_t)M_TOK * K_DIM;                // 32 MiB
  float* mid = (float*)(wb + (size_t)N_DIM * K_DIM);    // 256 KiB

  k_conv_w<<<2048, 256, 0, stream>>>(Wm, wb, (N_DIM * K_DIM) / 4);
  k_prep_x<<<M_TOK, 256, 0, stream>>>(x, WA, xb, mid);
  dim3 grid((M_TOK / 256) * (N_DIM / 256));             // 512 blocks
  k_gemm<<<grid, 512, 0, stream>>>(xb, wb, bmain, mask, mid, WB, out);
}

// Round 3
// 353.600 us; speedup vs baseline: 1.2407x; 1.0239x over previous
//
#include <hip/hip_runtime.h>

typedef unsigned short u16;
typedef unsigned int   u32;
typedef unsigned long long u64;
typedef __bf16 bf16x8 __attribute__((ext_vector_type(8)));
typedef float  f32x4  __attribute__((ext_vector_type(4)));

#define AS1 __attribute__((address_space(1)))
#define AS3 __attribute__((address_space(3)))

#define M_TOK 8192
#define K_DIM 4096
#define N_DIM 4096
#define BK    32
#define NKT   (K_DIM / BK)   // 128

static __device__ __forceinline__ u16 f2bf(float f) {
  u32 u = __builtin_bit_cast(u32, f);
  return (u16)((u + (0x7FFFu + ((u >> 16) & 1u))) >> 16);
}

// global -> LDS direct copy, 16B per lane. LDS dest is wave-uniform base;
// HW stores lane l at dest + l*16 (linear, rule #21).
static __device__ __forceinline__ void gld_lds16(const void* g, void* l) {
  __builtin_amdgcn_global_load_lds((AS1 u32*)(u64)g, (AS3 u32*)(u32)(u64)l, 16, 0, 0);
}

// ---- W_main f32 -> bf16 ----
__global__ __launch_bounds__(256) void k_conv_w(const float* __restrict__ W,
                                                u16* __restrict__ Wb, int n4) {
  const float4* W4 = (const float4*)W;
  ushort4* Wb4 = (ushort4*)Wb;
  int i = blockIdx.x * 256 + threadIdx.x;
  const int stride = gridDim.x * 256;
  for (; i < n4; i += stride) {
    float4 v = W4[i];
    ushort4 o;
    o.x = f2bf(v.x); o.y = f2bf(v.y); o.z = f2bf(v.z); o.w = f2bf(v.w);
    Wb4[i] = o;
  }
}

// ---- per token row: x f32 -> bf16, and mid[m][r] = 2 * dot(x[m], W_A[r]) ----
__global__ __launch_bounds__(256) void k_prep_x(const float* __restrict__ x,
                                                const float* __restrict__ WA,
                                                u16* __restrict__ xb,
                                                float* __restrict__ mid) {
  const int m = blockIdx.x;
  const int t = threadIdx.x;
  const float4* xr = (const float4*)(x + (size_t)m * K_DIM);
  ushort4* xbr = (ushort4*)(xb + (size_t)m * K_DIM);
  float a[8] = {0.f,0.f,0.f,0.f,0.f,0.f,0.f,0.f};
  #pragma unroll
  for (int i = 0; i < 4; ++i) {
    const int k4 = t + i * 256;
    float4 v = xr[k4];
    ushort4 o;
    o.x = f2bf(v.x); o.y = f2bf(v.y); o.z = f2bf(v.z); o.w = f2bf(v.w);
    xbr[k4] = o;
    #pragma unroll
    for (int r = 0; r < 8; ++r) {
      float4 wv = ((const float4*)(WA + (size_t)r * K_DIM))[k4];
      a[r] += v.x * wv.x + v.y * wv.y + v.z * wv.z + v.w * wv.w;
    }
  }
  #pragma unroll
  for (int r = 0; r < 8; ++r) {
    #pragma unroll
    for (int off = 32; off > 0; off >>= 1)
      a[r] += __shfl_down(a[r], off);
  }
  __shared__ float red[4][8];
  const int w = t >> 6, l = t & 63;
  if (l == 0) {
    #pragma unroll
    for (int r = 0; r < 8; ++r) red[w][r] = a[r];
  }
  __syncthreads();
  if (t < 8)
    mid[(size_t)m * 8 + t] = 2.0f * (red[0][t] + red[1][t] + red[2][t] + red[3][t]);
}

// ---- main GEMM: 256x256 tile, BK=32, 8 waves (2Mx4N), 4-deep LDS ring,
// counted-vmcnt pipeline (T3+T4) + setprio (T5) + XCD swizzle (T1)
// + T2-analog LDS XOR swizzle for BK=32 rows. ----
//
// LDS swizzle (both-sides-or-neither, rule #21): involution on the byte
// address within each 8KB stage quarter-block:
//   S(a) = a ^ (((a>>7)&3)<<4)    (16B-chunk idx ^= row bits [1:2])
// global_load_lds writes linearly at t*16, so the SOURCE global chunk is
// pre-permuted: c = (t&3) ^ ((t>>3)&3)  (each 4-lane group still covers one
// contiguous 64B row-segment -> fully coalesced). Reads apply the same XOR:
// col_u16 = (fq ^ ((fr>>1)&3))*8 -- wave-invariant (frag row bases are
// multiples of 16, so row bits [1:2] == fr bits [1:2]).
// Bank check, lanes 0-15 (fq=0): quads (4*row + (row>>1&3)) mod 8 =
// {0,4,1,5,2,6,3,7} -> 2 lanes/quad = conflict-free (m136: 2-way is free).
//
// Wait ledger (per wave, 4 gld_lds per tile, FIFO vmcnt retire):
//   prologue: issue tiles 0,1,2 (12 loads); vmcnt(8) -> tile0 resident.
//   during tile kt: issue tile kt+3 into buf (kt+3)&3 (= buf of kt-1,
//     whose reads finished before kt began -> no read/write race).
//   end of kt: need tile kt+1 resident; younger = tiles kt+2,kt+3 = 8
//     -> vmcnt(8). Tail: 8 -> 4 -> 0.
__global__ __launch_bounds__(512, 2) void k_gemm(
    const u16* __restrict__ A, const u16* __restrict__ B,
    const float* __restrict__ bias, const int* __restrict__ mask,
    const float* __restrict__ mid, const float* __restrict__ WBw,
    float* __restrict__ out) {
  __shared__ u16 smem[4][2][256][BK];   // [buf][A=0/B=1][row][k] = 128 KiB

  const int t = threadIdx.x;
  const int wid = t >> 6, l = t & 63;
  const int wr = wid >> 2, wc = wid & 3;   // 2x4 wave grid -> 128x64 out/wave
  const int fr = l & 15, fq = l >> 4;

  // T1: XCD-aware swizzle (512 blocks, 512%8==0 -> simple bijective form)
  const int bid = blockIdx.x;
  const int swz = (bid & 7) * 64 + (bid >> 3);
  const int bm = swz >> 4, bn = swz & 15;

  const char* Ag = (const char*)(A + (size_t)bm * 256 * K_DIM);
  const char* Bg = (const char*)(B + (size_t)bn * 256 * K_DIM);
  const size_t rowb = (size_t)K_DIM * 2;

  // staging: round q in {0:A-lo,1:A-hi,2:B-lo,3:B-hi}; 512 thr x 16B = 8KB
  // = one 128-row x 64B half. thread t covers row t>>2; source 16B-chunk is
  // the T2 pre-swizzle (t&3)^((t>>3)&3).
  const int srow = t >> 2;
  const int schk = (((t & 3) ^ ((t >> 3) & 3)) * 16);
  const char* gsrc[4] = {
    Ag + (size_t)srow * rowb + schk,
    Ag + (size_t)(128 + srow) * rowb + schk,
    Bg + (size_t)srow * rowb + schk,
    Bg + (size_t)(128 + srow) * rowb + schk };
  char* lbase = (char*)&smem[0][0][0][0] + wid * 1024;

  #define STAGE(bufv, nktv, q) \
    gld_lds16(gsrc[q] + (size_t)(nktv) * (BK * 2), \
              lbase + (bufv) * 32768 + (q) * 8192)

  f32x4 acc[8][4];
  #pragma unroll
  for (int m = 0; m < 8; ++m)
    #pragma unroll
    for (int n = 0; n < 4; ++n)
      acc[m][n] = (f32x4){0.f, 0.f, 0.f, 0.f};

  // prologue: tiles 0..2
  #pragma unroll
  for (int pk = 0; pk < 3; ++pk) {
    STAGE(pk, pk, 0); STAGE(pk, pk, 1); STAGE(pk, pk, 2); STAGE(pk, pk, 3);
  }
  asm volatile("s_waitcnt vmcnt(8)");
  __builtin_amdgcn_s_barrier();

  // T2 read-side swizzled column (u16 units), wave-invariant:
  const int csw = (fq ^ ((fr >> 1) & 3)) * 8;

  bf16x8 bfv[4];
  for (int kt = 0; kt < NKT; ++kt) {
    const int buf = kt & 3;
    const int nkt = kt + 3;
    const int nbuf = nkt & 3;
    const bool st = nkt < NKT;
    const u16* Ab = &smem[buf][0][wr * 128 + fr][csw];
    const u16* Bb = &smem[buf][1][wc * 64 + fr][csw];
    bf16x8 af[4];

    // ---- phase 0: frags m0..3 + all b; stage A halves of kt+3 ----
    #pragma unroll
    for (int m = 0; m < 4; ++m) af[m] = *(const bf16x8*)(Ab + m * 16 * BK);
    #pragma unroll
    for (int n = 0; n < 4; ++n) bfv[n] = *(const bf16x8*)(Bb + n * 16 * BK);
    if (st) { STAGE(nbuf, nkt, 0); STAGE(nbuf, nkt, 1); }
    __builtin_amdgcn_s_barrier();
    asm volatile("s_waitcnt lgkmcnt(0)");
    __builtin_amdgcn_s_setprio(1);
    #pragma unroll
    for (int m = 0; m < 4; ++m)
      #pragma unroll
      for (int n = 0; n < 4; ++n)
        acc[m][n] = __builtin_amdgcn_mfma_f32_16x16x32_bf16(af[m], bfv[n], acc[m][n], 0, 0, 0);
    __builtin_amdgcn_s_setprio(0);
    __builtin_amdgcn_s_barrier();

    // ---- phase 1: frags m4..7; stage B halves of kt+3; tile-end vmcnt ----
    #pragma unroll
    for (int m = 0; m < 4; ++m) af[m] = *(const bf16x8*)(Ab + (4 + m) * 16 * BK);
    if (st) { STAGE(nbuf, nkt, 2); STAGE(nbuf, nkt, 3); }
    if (kt <= NKT - 4)      asm volatile("s_waitcnt vmcnt(8)");
    else if (kt == NKT - 3) asm volatile("s_waitcnt vmcnt(4)");
    else if (kt == NKT - 2) asm volatile("s_waitcnt vmcnt(0)");
    __builtin_amdgcn_s_barrier();
    asm volatile("s_waitcnt lgkmcnt(0)");
    __builtin_amdgcn_s_setprio(1);
    #pragma unroll
    for (int m = 0; m < 4; ++m)
      #pragma unroll
      for (int n = 0; n < 4; ++n)
        acc[4 + m][n] = __builtin_amdgcn_mfma_f32_16x16x32_bf16(af[m], bfv[n], acc[4 + m][n], 0, 0, 0);
    __builtin_amdgcn_s_setprio(0);
    __builtin_amdgcn_s_barrier();
  }
  #undef STAGE

  // ---- epilogue: bias + masked rank-8 LoRA, fp32 out ----
  const int gn0 = bn * 256 + wc * 64;
  const size_t gm0 = (size_t)bm * 256 + wr * 128;
  float wbv[4][8]; float bv[4];
  #pragma unroll
  for (int n = 0; n < 4; ++n) {
    const int gn = gn0 + n * 16 + fr;
    bv[n] = bias[gn];
    const float4 w0 = ((const float4*)(WBw + (size_t)gn * 8))[0];
    const float4 w1 = ((const float4*)(WBw + (size_t)gn * 8))[1];
    wbv[n][0] = w0.x; wbv[n][1] = w0.y; wbv[n][2] = w0.z; wbv[n][3] = w0.w;
    wbv[n][4] = w1.x; wbv[n][5] = w1.y; wbv[n][6] = w1.z; wbv[n][7] = w1.w;
  }
  #pragma unroll
  for (int m = 0; m < 8; ++m) {
    #pragma unroll
    for (int j = 0; j < 4; ++j) {
      const size_t gm = gm0 + m * 16 + fq * 4 + j;   // C/D row = (l>>4)*4+reg
      const int msk = mask[gm];
      const float4 m0 = ((const float4*)(mid + gm * 8))[0];
      const float4 m1 = ((const float4*)(mid + gm * 8))[1];
      float* orow = out + gm * (size_t)N_DIM;
      #pragma unroll
      for (int n = 0; n < 4; ++n) {
        const float lora =
            m0.x * wbv[n][0] + m0.y * wbv[n][1] + m0.z * wbv[n][2] + m0.w * wbv[n][3] +
            m1.x * wbv[n][4] + m1.y * wbv[n][5] + m1.z * wbv[n][6] + m1.w * wbv[n][7];
        orow[gn0 + n * 16 + fr] = acc[m][n][j] + bv[n] + (msk ? lora : 0.0f);
      }
    }
  }
}

extern "C" void kernel_launch(void* const* d_in, const int* in_sizes, int n_in,
                              void* d_out, int out_size, void* d_ws, size_t ws_size,
                              hipStream_t stream) {
  (void)in_sizes; (void)n_in; (void)out_size; (void)ws_size;
  const float* x     = (const float*)d_in[0];
  const int*   mask  = (const int*)d_in[1];
  const float* Wm    = (const float*)d_in[2];
  const float* bmain = (const float*)d_in[3];
  const float* WA    = (const float*)d_in[4];
  const float* WB    = (const float*)d_in[5];
  float* out = (float*)d_out;

  u16* xb  = (u16*)d_ws;                                // 64 MiB
  u16* wb  = xb + (size_t)M_TOK * K_DIM;                // 32 MiB
  float* mid = (float*)(wb + (size_t)N_DIM * K_DIM);    // 256 KiB

  k_conv_w<<<2048, 256, 0, stream>>>(Wm, wb, (N_DIM * K_DIM) / 4);
  k_prep_x<<<M_TOK, 256, 0, stream>>>(x, WA, xb, mid);
  dim3 grid((M_TOK / 256) * (N_DIM / 256));             // 512 blocks
  k_gemm<<<grid, 512, 0, stream>>>(xb, wb, bmain, mask, mid, WB, out);
}

// Round 4
// 336.570 us; speedup vs baseline: 1.3035x; 1.0506x over previous
//
#include <hip/hip_runtime.h>

typedef unsigned short u16;
typedef unsigned int   u32;
typedef unsigned long long u64;
typedef __bf16 bf16x8 __attribute__((ext_vector_type(8)));
typedef float  f32x4  __attribute__((ext_vector_type(4)));

#define AS1 __attribute__((address_space(1)))
#define AS3 __attribute__((address_space(3)))

#define M_TOK 8192
#define K_DIM 4096
#define N_DIM 4096
#define BK    32
#define NKT   (K_DIM / BK)   // 128

static __device__ __forceinline__ u16 f2bf(float f) {
  u32 u = __builtin_bit_cast(u32, f);
  return (u16)((u + (0x7FFFu + ((u >> 16) & 1u))) >> 16);
}

// global -> LDS direct copy, 16B per lane. LDS dest is wave-uniform base;
// HW stores lane l at dest + l*16 (linear, rule #21).
static __device__ __forceinline__ void gld_lds16(const void* g, void* l) {
  __builtin_amdgcn_global_load_lds((AS1 u32*)(u64)g, (AS3 u32*)(u32)(u64)l, 16, 0, 0);
}

// ---- W_main f32 -> bf16 ----
__global__ __launch_bounds__(256) void k_conv_w(const float* __restrict__ W,
                                                u16* __restrict__ Wb, int n4) {
  const float4* W4 = (const float4*)W;
  ushort4* Wb4 = (ushort4*)Wb;
  int i = blockIdx.x * 256 + threadIdx.x;
  const int stride = gridDim.x * 256;
  for (; i < n4; i += stride) {
    float4 v = W4[i];
    ushort4 o;
    o.x = f2bf(v.x); o.y = f2bf(v.y); o.z = f2bf(v.z); o.w = f2bf(v.w);
    Wb4[i] = o;
  }
}

// ---- per token row: x f32 -> bf16, and mid[m][r] = 2 * dot(x[m], W_A[r]) ----
__global__ __launch_bounds__(256) void k_prep_x(const float* __restrict__ x,
                                                const float* __restrict__ WA,
                                                u16* __restrict__ xb,
                                                float* __restrict__ mid) {
  const int m = blockIdx.x;
  const int t = threadIdx.x;
  const float4* xr = (const float4*)(x + (size_t)m * K_DIM);
  ushort4* xbr = (ushort4*)(xb + (size_t)m * K_DIM);
  float a[8] = {0.f,0.f,0.f,0.f,0.f,0.f,0.f,0.f};
  #pragma unroll
  for (int i = 0; i < 4; ++i) {
    const int k4 = t + i * 256;
    float4 v = xr[k4];
    ushort4 o;
    o.x = f2bf(v.x); o.y = f2bf(v.y); o.z = f2bf(v.z); o.w = f2bf(v.w);
    xbr[k4] = o;
    #pragma unroll
    for (int r = 0; r < 8; ++r) {
      float4 wv = ((const float4*)(WA + (size_t)r * K_DIM))[k4];
      a[r] += v.x * wv.x + v.y * wv.y + v.z * wv.z + v.w * wv.w;
    }
  }
  #pragma unroll
  for (int r = 0; r < 8; ++r) {
    #pragma unroll
    for (int off = 32; off > 0; off >>= 1)
      a[r] += __shfl_down(a[r], off);
  }
  __shared__ float red[4][8];
  const int w = t >> 6, l = t & 63;
  if (l == 0) {
    #pragma unroll
    for (int r = 0; r < 8; ++r) red[w][r] = a[r];
  }
  __syncthreads();
  if (t < 8)
    mid[(size_t)m * 8 + t] = 2.0f * (red[0][t] + red[1][t] + red[2][t] + red[3][t]);
}

// ---- main GEMM: 256x256 tile, BK=32, 8 waves (2Mx4N), 4-deep LDS ring,
// counted-vmcnt pipeline (T3+T4) + setprio (T5) + XCD swizzle (T1)
// + T2-analog LDS XOR swizzle (R3: conflicts 2.5e7 -> 0).
// R4: ring hand-unrolled by its period (4) with LITERAL buffer indices and
// running global stage pointers -> all LDS addresses fold to immediates,
// no per-tile VALU address chains, no branches in the steady loop.
// Schedule/ledger identical to R3:
//   during tile kt stage kt+3 into buf (kt+3)&3 (= buf of kt-1, reads done);
//   end of kt wait vmcnt(8) (tiles kt+2,kt+3 = 8 loads in flight);
//   tail ladder 8 -> 4 -> 0 on peeled tiles 125/126.
__global__ __launch_bounds__(512, 2) void k_gemm(
    const u16* __restrict__ A, const u16* __restrict__ B,
    const float* __restrict__ bias, const int* __restrict__ mask,
    const float* __restrict__ mid, const float* __restrict__ WBw,
    float* __restrict__ out) {
  __shared__ u16 smem[4][2][256][BK];   // [buf][A=0/B=1][row][k] = 128 KiB

  const int t = threadIdx.x;
  const int wid = t >> 6, l = t & 63;
  const int wr = wid >> 2, wc = wid & 3;   // 2x4 wave grid -> 128x64 out/wave
  const int fr = l & 15, fq = l >> 4;

  // T1: XCD-aware swizzle (512 blocks, 512%8==0 -> bijective)
  const int bid = blockIdx.x;
  const int swz = (bid & 7) * 64 + (bid >> 3);
  const int bm = swz >> 4, bn = swz & 15;

  const char* Ag = (const char*)(A + (size_t)bm * 256 * K_DIM);
  const char* Bg = (const char*)(B + (size_t)bn * 256 * K_DIM);
  const size_t rowb = (size_t)K_DIM * 2;

  // staging: q in {A-lo, A-hi, B-lo, B-hi}; 512 thr x 16B = 8KB per q.
  // thread t covers row t>>2; source 16B-chunk is the T2 pre-swizzle
  // (t&3)^((t>>3)&3) (4-lane groups stay within one 64B row-segment).
  const int srow = t >> 2;
  const int schk = (((t & 3) ^ ((t >> 3) & 3)) * 16);
  const char* bA0 = Ag + (size_t)srow * rowb + schk;
  const char* bA1 = Ag + (size_t)(128 + srow) * rowb + schk;
  const char* bB0 = Bg + (size_t)srow * rowb + schk;
  const char* bB1 = Bg + (size_t)(128 + srow) * rowb + schk;
  char* lbase = (char*)&smem[0][0][0][0] + wid * 1024;

  f32x4 acc[8][4];
  #pragma unroll
  for (int m = 0; m < 8; ++m)
    #pragma unroll
    for (int n = 0; n < 4; ++n)
      acc[m][n] = (f32x4){0.f, 0.f, 0.f, 0.f};

  // prologue: tiles 0..2 into bufs 0..2
  #pragma unroll
  for (int pk = 0; pk < 3; ++pk) {
    gld_lds16(bA0 + pk * 64, lbase + pk * 32768);
    gld_lds16(bA1 + pk * 64, lbase + pk * 32768 + 8192);
    gld_lds16(bB0 + pk * 64, lbase + pk * 32768 + 16384);
    gld_lds16(bB1 + pk * 64, lbase + pk * 32768 + 24576);
  }
  asm volatile("s_waitcnt vmcnt(8)");
  __builtin_amdgcn_s_barrier();

  // T2 read-side swizzled column (u16 units), wave-invariant
  const int csw = (fq ^ ((fr >> 1) & 3)) * 8;

  // running stage pointers, pre-offset to tile 3 (= kt+3 at ktb=0)
  const char* gA0 = bA0 + 192;
  const char* gA1 = bA1 + 192;
  const char* gB0 = bB0 + 192;
  const char* gB1 = bB1 + 192;

  // One K32-tile: literal BUFC (compute buf), NB (stage buf), GOFF (stage
  // byte offset from running pointers), DOSTAGE, WAIT statement.
  #define K_TILE(BUFC, NB, DOSTAGE, GOFF, WAIT) do {                         \
    const u16* Ab_ = &smem[BUFC][0][wr * 128 + fr][csw];                     \
    const u16* Bb_ = &smem[BUFC][1][wc * 64 + fr][csw];                      \
    bf16x8 af_[4], bf_[4];                                                   \
    _Pragma("unroll")                                                        \
    for (int m = 0; m < 4; ++m) af_[m] = *(const bf16x8*)(Ab_ + m * 16 * BK);\
    _Pragma("unroll")                                                        \
    for (int n = 0; n < 4; ++n) bf_[n] = *(const bf16x8*)(Bb_ + n * 16 * BK);\
    if (DOSTAGE) {                                                           \
      gld_lds16(gA0 + (GOFF), lbase + (NB) * 32768);                         \
      gld_lds16(gA1 + (GOFF), lbase + (NB) * 32768 + 8192);                  \
    }                                                                        \
    __builtin_amdgcn_s_barrier();                                            \
    asm volatile("s_waitcnt lgkmcnt(0)");                                    \
    __builtin_amdgcn_s_setprio(1);                                           \
    _Pragma("unroll")                                                        \
    for (int m = 0; m < 4; ++m)                                              \
      _Pragma("unroll")                                                      \
      for (int n = 0; n < 4; ++n)                                            \
        acc[m][n] = __builtin_amdgcn_mfma_f32_16x16x32_bf16(                 \
            af_[m], bf_[n], acc[m][n], 0, 0, 0);                             \
    __builtin_amdgcn_s_setprio(0);                                           \
    __builtin_amdgcn_s_barrier();                                            \
    _Pragma("unroll")                                                        \
    for (int m = 0; m < 4; ++m)                                              \
      af_[m] = *(const bf16x8*)(Ab_ + (4 + m) * 16 * BK);                    \
    if (DOSTAGE) {                                                           \
      gld_lds16(gB0 + (GOFF), lbase + (NB) * 32768 + 16384);                 \
      gld_lds16(gB1 + (GOFF), lbase + (NB) * 32768 + 24576);                 \
    }                                                                        \
    WAIT;                                                                    \
    __builtin_amdgcn_s_barrier();                                            \
    asm volatile("s_waitcnt lgkmcnt(0)");                                    \
    __builtin_amdgcn_s_setprio(1);                                           \
    _Pragma("unroll")                                                        \
    for (int m = 0; m < 4; ++m)                                              \
      _Pragma("unroll")                                                      \
      for (int n = 0; n < 4; ++n)                                            \
        acc[4 + m][n] = __builtin_amdgcn_mfma_f32_16x16x32_bf16(             \
            af_[m], bf_[n], acc[4 + m][n], 0, 0, 0);                         \
    __builtin_amdgcn_s_setprio(0);                                           \
    __builtin_amdgcn_s_barrier();                                            \
  } while (0)

  #define VM8 asm volatile("s_waitcnt vmcnt(8)")
  #define VM4 asm volatile("s_waitcnt vmcnt(4)")
  #define VM0 asm volatile("s_waitcnt vmcnt(0)")

  // steady: 31 groups of 4 tiles (kt = 0..123), all stage, all vmcnt(8)
  for (int ktb = 0; ktb < NKT - 4; ktb += 4) {
    K_TILE(0, 3, true, 0,   VM8);
    K_TILE(1, 0, true, 64,  VM8);
    K_TILE(2, 1, true, 128, VM8);
    K_TILE(3, 2, true, 192, VM8);
    gA0 += 256; gA1 += 256; gB0 += 256; gB1 += 256;
  }
  // peeled tail: kt = 124 (stage tile 127 at GOFF 0), 125, 126, 127
  K_TILE(0, 3, true,  0, VM8);
  K_TILE(1, 0, false, 0, VM4);
  K_TILE(2, 1, false, 0, VM0);
  K_TILE(3, 2, false, 0, ((void)0));

  #undef K_TILE
  #undef VM8
  #undef VM4
  #undef VM0

  // ---- epilogue: bias + masked rank-8 LoRA, fp32 out ----
  const int gn0 = bn * 256 + wc * 64;
  const size_t gm0 = (size_t)bm * 256 + wr * 128;
  float wbv[4][8]; float bv[4];
  #pragma unroll
  for (int n = 0; n < 4; ++n) {
    const int gn = gn0 + n * 16 + fr;
    bv[n] = bias[gn];
    const float4 w0 = ((const float4*)(WBw + (size_t)gn * 8))[0];
    const float4 w1 = ((const float4*)(WBw + (size_t)gn * 8))[1];
    wbv[n][0] = w0.x; wbv[n][1] = w0.y; wbv[n][2] = w0.z; wbv[n][3] = w0.w;
    wbv[n][4] = w1.x; wbv[n][5] = w1.y; wbv[n][6] = w1.z; wbv[n][7] = w1.w;
  }
  #pragma unroll
  for (int m = 0; m < 8; ++m) {
    #pragma unroll
    for (int j = 0; j < 4; ++j) {
      const size_t gm = gm0 + m * 16 + fq * 4 + j;   // C/D row = (l>>4)*4+reg
      const int msk = mask[gm];
      const float4 m0 = ((const float4*)(mid + gm * 8))[0];
      const float4 m1 = ((const float4*)(mid + gm * 8))[1];
      float* orow = out + gm * (size_t)N_DIM;
      #pragma unroll
      for (int n = 0; n < 4; ++n) {
        const float lora =
            m0.x * wbv[n][0] + m0.y * wbv[n][1] + m0.z * wbv[n][2] + m0.w * wbv[n][3] +
            m1.x * wbv[n][4] + m1.y * wbv[n][5] + m1.z * wbv[n][6] + m1.w * wbv[n][7];
        orow[gn0 + n * 16 + fr] = acc[m][n][j] + bv[n] + (msk ? lora : 0.0f);
      }
    }
  }
}

extern "C" void kernel_launch(void* const* d_in, const int* in_sizes, int n_in,
                              void* d_out, int out_size, void* d_ws, size_t ws_size,
                              hipStream_t stream) {
  (void)in_sizes; (void)n_in; (void)out_size; (void)ws_size;
  const float* x     = (const float*)d_in[0];
  const int*   mask  = (const int*)d_in[1];
  const float* Wm    = (const float*)d_in[2];
  const float* bmain = (const float*)d_in[3];
  const float* WA    = (const float*)d_in[4];
  const float* WB    = (const float*)d_in[5];
  float* out = (float*)d_out;

  u16* xb  = (u16*)d_ws;                                // 64 MiB
  u16* wb  = xb + (size_t)M_TOK * K_DIM;                // 32 MiB
  float* mid = (float*)(wb + (size_t)N_DIM * K_DIM);    // 256 KiB

  k_conv_w<<<2048, 256, 0, stream>>>(Wm, wb, (N_DIM * K_DIM) / 4);
  k_prep_x<<<M_TOK, 256, 0, stream>>>(x, WA, xb, mid);
  dim3 grid((M_TOK / 256) * (N_DIM / 256));             // 512 blocks
  k_gemm<<<grid, 512, 0, stream>>>(xb, wb, bmain, mask, mid, WB, out);
}

// Round 5
// 325.877 us; speedup vs baseline: 1.3462x; 1.0328x over previous
//
#include <hip/hip_runtime.h>

typedef unsigned short u16;
typedef unsigned int   u32;
typedef unsigned long long u64;
typedef __bf16 bf16x8 __attribute__((ext_vector_type(8)));
typedef float  f32x4  __attribute__((ext_vector_type(4)));

#define AS1 __attribute__((address_space(1)))
#define AS3 __attribute__((address_space(3)))

#define M_TOK 8192
#define K_DIM 4096
#define N_DIM 4096
#define BK    32
#define NKT   (K_DIM / BK)   // 128

static __device__ __forceinline__ u16 f2bf(float f) {
  u32 u = __builtin_bit_cast(u32, f);
  return (u16)((u + (0x7FFFu + ((u >> 16) & 1u))) >> 16);
}

// global -> LDS direct copy, 16B per lane. LDS dest is wave-uniform base;
// HW stores lane l at dest + l*16 (linear, rule #21).
static __device__ __forceinline__ void gld_lds16(const void* g, void* l) {
  __builtin_amdgcn_global_load_lds((AS1 u32*)(u64)g, (AS3 u32*)(u32)(u64)l, 16, 0, 0);
}

// ---- fused prep: blocks [0, M_TOK) do per-token x->bf16 + LoRA mid;
//      blocks [M_TOK, M_TOK+2048) convert W_main f32->bf16 (grid-stride). ----
__global__ __launch_bounds__(256) void k_prep(const float* __restrict__ x,
                                              const float* __restrict__ WA,
                                              const float* __restrict__ W,
                                              u16* __restrict__ xb,
                                              float* __restrict__ mid,
                                              u16* __restrict__ Wb) {
  const int t = threadIdx.x;
  if (blockIdx.x >= M_TOK) {
    // ---- W_main conversion ----
    const int cb = blockIdx.x - M_TOK;           // 0..2047
    const float4* W4 = (const float4*)W;
    ushort4* Wb4 = (ushort4*)Wb;
    const int n4 = (N_DIM * K_DIM) / 4;
    int i = cb * 256 + t;
    for (; i < n4; i += 2048 * 256) {
      float4 v = W4[i];
      ushort4 o;
      o.x = f2bf(v.x); o.y = f2bf(v.y); o.z = f2bf(v.z); o.w = f2bf(v.w);
      Wb4[i] = o;
    }
    return;
  }
  // ---- per-token: x f32->bf16 and mid[m][r] = 2 * dot(x[m], W_A[r]) ----
  const int m = blockIdx.x;
  const float4* xr = (const float4*)(x + (size_t)m * K_DIM);
  ushort4* xbr = (ushort4*)(xb + (size_t)m * K_DIM);
  float a[8] = {0.f,0.f,0.f,0.f,0.f,0.f,0.f,0.f};
  #pragma unroll
  for (int i = 0; i < 4; ++i) {
    const int k4 = t + i * 256;
    float4 v = xr[k4];
    ushort4 o;
    o.x = f2bf(v.x); o.y = f2bf(v.y); o.z = f2bf(v.z); o.w = f2bf(v.w);
    xbr[k4] = o;
    #pragma unroll
    for (int r = 0; r < 8; ++r) {
      float4 wv = ((const float4*)(WA + (size_t)r * K_DIM))[k4];
      a[r] += v.x * wv.x + v.y * wv.y + v.z * wv.z + v.w * wv.w;
    }
  }
  #pragma unroll
  for (int r = 0; r < 8; ++r) {
    #pragma unroll
    for (int off = 32; off > 0; off >>= 1)
      a[r] += __shfl_down(a[r], off);
  }
  __shared__ float red[4][8];
  const int w = t >> 6, l = t & 63;
  if (l == 0) {
    #pragma unroll
    for (int r = 0; r < 8; ++r) red[w][r] = a[r];
  }
  __syncthreads();
  if (t < 8)
    mid[(size_t)m * 8 + t] = 2.0f * (red[0][t] + red[1][t] + red[2][t] + red[3][t]);
}

// ---- main GEMM: 256x256 tile, BK=32, 8 waves (2Mx4N), 4-deep LDS ring,
// counted-vmcnt pipeline (T3+T4) + setprio (T5) + XCD swizzle (T1)
// + LDS XOR swizzle (R3: conflicts -> 0) + literal-index unroll (R4).
// R5: ONE barrier per K-tile (mid-tile barriers were template ritual —
// correctness needs only the tile-boundary barrier; see ledger below).
// Per tile: 12 ds_read_b128 -> 4 gld_lds issues -> 32-MFMA cluster
// (compiler interleaves via fine lgkmcnt) -> vmcnt(8) -> barrier.
//
// Ledger (4 gld_lds per tile per wave, FIFO retire):
//   reads of tile kt are safe: its staging (issued at kt-3) was covered by
//     vmcnt(8) at end of kt-1 + the boundary barrier.
//   staging into buf[(kt+3)&3] = buf[kt-1] is safe: tile kt-1's LDS reads
//     drained (lgkm) before its MFMA, which precedes the boundary barrier.
//   end of kt: need kt+1 resident; younger = kt+2,kt+3 = 8 -> vmcnt(8).
//   Tail ladder 8 -> 4 -> 0 on tiles 125/126.
__global__ __launch_bounds__(512, 2) void k_gemm(
    const u16* __restrict__ A, const u16* __restrict__ B,
    const float* __restrict__ bias, const int* __restrict__ mask,
    const float* __restrict__ mid, const float* __restrict__ WBw,
    float* __restrict__ out) {
  __shared__ u16 smem[4][2][256][BK];   // [buf][A=0/B=1][row][k] = 128 KiB

  const int t = threadIdx.x;
  const int wid = t >> 6, l = t & 63;
  const int wr = wid >> 2, wc = wid & 3;   // 2x4 wave grid -> 128x64 out/wave
  const int fr = l & 15, fq = l >> 4;

  // T1: XCD-aware swizzle (512 blocks, 512%8==0 -> bijective)
  const int bid = blockIdx.x;
  const int swz = (bid & 7) * 64 + (bid >> 3);
  const int bm = swz >> 4, bn = swz & 15;

  const char* Ag = (const char*)(A + (size_t)bm * 256 * K_DIM);
  const char* Bg = (const char*)(B + (size_t)bn * 256 * K_DIM);
  const size_t rowb = (size_t)K_DIM * 2;

  // staging: q in {A-lo, A-hi, B-lo, B-hi}; 512 thr x 16B = 8KB per q.
  // thread t covers row t>>2; source 16B-chunk is the T2 pre-swizzle
  // (t&3)^((t>>3)&3) (4-lane groups stay within one 64B row-segment).
  const int srow = t >> 2;
  const int schk = (((t & 3) ^ ((t >> 3) & 3)) * 16);
  const char* bA0 = Ag + (size_t)srow * rowb + schk;
  const char* bA1 = Ag + (size_t)(128 + srow) * rowb + schk;
  const char* bB0 = Bg + (size_t)srow * rowb + schk;
  const char* bB1 = Bg + (size_t)(128 + srow) * rowb + schk;
  char* lbase = (char*)&smem[0][0][0][0] + wid * 1024;

  f32x4 acc[8][4];
  #pragma unroll
  for (int m = 0; m < 8; ++m)
    #pragma unroll
    for (int n = 0; n < 4; ++n)
      acc[m][n] = (f32x4){0.f, 0.f, 0.f, 0.f};

  // prologue: tiles 0..2 into bufs 0..2
  #pragma unroll
  for (int pk = 0; pk < 3; ++pk) {
    gld_lds16(bA0 + pk * 64, lbase + pk * 32768);
    gld_lds16(bA1 + pk * 64, lbase + pk * 32768 + 8192);
    gld_lds16(bB0 + pk * 64, lbase + pk * 32768 + 16384);
    gld_lds16(bB1 + pk * 64, lbase + pk * 32768 + 24576);
  }
  asm volatile("s_waitcnt vmcnt(8)");
  __builtin_amdgcn_s_barrier();

  // T2 read-side swizzled column (u16 units), wave-invariant
  const int csw = (fq ^ ((fr >> 1) & 3)) * 8;

  // running stage pointers, pre-offset to tile 3 (= kt+3 at ktb=0)
  const char* gA0 = bA0 + 192;
  const char* gA1 = bA1 + 192;
  const char* gB0 = bB0 + 192;
  const char* gB1 = bB1 + 192;

  // One K32-tile, single-barrier form.
  #define K_TILE(BUFC, NB, DOSTAGE, GOFF, WAIT) do {                         \
    const u16* Ab_ = &smem[BUFC][0][wr * 128 + fr][csw];                     \
    const u16* Bb_ = &smem[BUFC][1][wc * 64 + fr][csw];                      \
    bf16x8 af_[8], bf_[4];                                                   \
    _Pragma("unroll")                                                        \
    for (int m = 0; m < 8; ++m) af_[m] = *(const bf16x8*)(Ab_ + m * 16 * BK);\
    _Pragma("unroll")                                                        \
    for (int n = 0; n < 4; ++n) bf_[n] = *(const bf16x8*)(Bb_ + n * 16 * BK);\
    if (DOSTAGE) {                                                           \
      gld_lds16(gA0 + (GOFF), lbase + (NB) * 32768);                         \
      gld_lds16(gA1 + (GOFF), lbase + (NB) * 32768 + 8192);                  \
      gld_lds16(gB0 + (GOFF), lbase + (NB) * 32768 + 16384);                 \
      gld_lds16(gB1 + (GOFF), lbase + (NB) * 32768 + 24576);                 \
    }                                                                        \
    __builtin_amdgcn_s_setprio(1);                                           \
    _Pragma("unroll")                                                        \
    for (int m = 0; m < 8; ++m)                                              \
      _Pragma("unroll")                                                      \
      for (int n = 0; n < 4; ++n)                                            \
        acc[m][n] = __builtin_amdgcn_mfma_f32_16x16x32_bf16(                 \
            af_[m], bf_[n], acc[m][n], 0, 0, 0);                             \
    __builtin_amdgcn_s_setprio(0);                                           \
    WAIT;                                                                    \
    __builtin_amdgcn_s_barrier();                                            \
  } while (0)

  #define VM8 asm volatile("s_waitcnt vmcnt(8)")
  #define VM4 asm volatile("s_waitcnt vmcnt(4)")
  #define VM0 asm volatile("s_waitcnt vmcnt(0)")

  // steady: 31 groups of 4 tiles (kt = 0..123), all stage, all vmcnt(8)
  for (int ktb = 0; ktb < NKT - 4; ktb += 4) {
    K_TILE(0, 3, true, 0,   VM8);
    K_TILE(1, 0, true, 64,  VM8);
    K_TILE(2, 1, true, 128, VM8);
    K_TILE(3, 2, true, 192, VM8);
    gA0 += 256; gA1 += 256; gB0 += 256; gB1 += 256;
  }
  // peeled tail: kt = 124 (stage tile 127 at GOFF 0), 125, 126, 127
  K_TILE(0, 3, true,  0, VM8);
  K_TILE(1, 0, false, 0, VM4);
  K_TILE(2, 1, false, 0, VM0);
  K_TILE(3, 2, false, 0, ((void)0));

  #undef K_TILE
  #undef VM8
  #undef VM4
  #undef VM0

  // ---- epilogue: bias + masked rank-8 LoRA, fp32 out ----
  const int gn0 = bn * 256 + wc * 64;
  const size_t gm0 = (size_t)bm * 256 + wr * 128;
  float wbv[4][8]; float bv[4];
  #pragma unroll
  for (int n = 0; n < 4; ++n) {
    const int gn = gn0 + n * 16 + fr;
    bv[n] = bias[gn];
    const float4 w0 = ((const float4*)(WBw + (size_t)gn * 8))[0];
    const float4 w1 = ((const float4*)(WBw + (size_t)gn * 8))[1];
    wbv[n][0] = w0.x; wbv[n][1] = w0.y; wbv[n][2] = w0.z; wbv[n][3] = w0.w;
    wbv[n][4] = w1.x; wbv[n][5] = w1.y; wbv[n][6] = w1.z; wbv[n][7] = w1.w;
  }
  #pragma unroll
  for (int m = 0; m < 8; ++m) {
    #pragma unroll
    for (int j = 0; j < 4; ++j) {
      const size_t gm = gm0 + m * 16 + fq * 4 + j;   // C/D row = (l>>4)*4+reg
      const int msk = mask[gm];
      const float4 m0 = ((const float4*)(mid + gm * 8))[0];
      const float4 m1 = ((const float4*)(mid + gm * 8))[1];
      float* orow = out + gm * (size_t)N_DIM;
      #pragma unroll
      for (int n = 0; n < 4; ++n) {
        const float lora =
            m0.x * wbv[n][0] + m0.y * wbv[n][1] + m0.z * wbv[n][2] + m0.w * wbv[n][3] +
            m1.x * wbv[n][4] + m1.y * wbv[n][5] + m1.z * wbv[n][6] + m1.w * wbv[n][7];
        orow[gn0 + n * 16 + fr] = acc[m][n][j] + bv[n] + (msk ? lora : 0.0f);
      }
    }
  }
}

extern "C" void kernel_launch(void* const* d_in, const int* in_sizes, int n_in,
                              void* d_out, int out_size, void* d_ws, size_t ws_size,
                              hipStream_t stream) {
  (void)in_sizes; (void)n_in; (void)out_size; (void)ws_size;
  const float* x     = (const float*)d_in[0];
  const int*   mask  = (const int*)d_in[1];
  const float* Wm    = (const float*)d_in[2];
  const float* bmain = (const float*)d_in[3];
  const float* WA    = (const float*)d_in[4];
  const float* WB    = (const float*)d_in[5];
  float* out = (float*)d_out;

  u16* xb  = (u16*)d_ws;                                // 64 MiB
  u16* wb  = xb + (size_t)M_TOK * K_DIM;                // 32 MiB
  float* mid = (float*)(wb + (size_t)N_DIM * K_DIM);    // 256 KiB

  k_prep<<<M_TOK + 2048, 256, 0, stream>>>(x, WA, Wm, xb, mid, wb);
  dim3 grid((M_TOK / 256) * (N_DIM / 256));             // 512 blocks
  k_gemm<<<grid, 512, 0, stream>>>(xb, wb, bmain, mask, mid, WB, out);
}